// Round 9
// baseline (901.224 us; speedup 1.0000x reference)
//
#include <hip/hip_runtime.h>
#include <hip/hip_bf16.h>

// Detect head — R9 DIAGNOSTIC ROUND.
// Baseline kernel = R8 (BM=64 x BN=96 anchor-aligned, BK=64, dbuf+2-phase
// prefetch, 40KB LDS, XCD swizzle, LDS-image epilogue + nt stores).
// Three variants launched back-to-back to ablate where the ~120us goes:
//   MODE1 x5 : K-loop core only (stage+MFMA), acc carried across reps.
//   MODE2 x6 : K-loop once + epilogue repeated (decode+LDS+nt stores to ws).
//   MODE0 x1 : real kernel, writes validated output.

typedef __attribute__((ext_vector_type(8))) short short8;
typedef __attribute__((ext_vector_type(4))) short short4v;
typedef __attribute__((ext_vector_type(4))) float f32x4;
typedef unsigned int u32;

__device__ __forceinline__ unsigned short f2bf(float f) {
    union { float f; unsigned u; } c; c.f = f;
    return (unsigned short)((c.u + 0x7fffu + ((c.u >> 16) & 1u)) >> 16);  // RTNE
}
__device__ __forceinline__ float sigm(float v) {
    return 1.0f / (1.0f + __expf(-v));
}
__device__ __forceinline__ void gload16(const void* g, void* l) {
    __builtin_amdgcn_global_load_lds(
        (const __attribute__((address_space(1))) u32*)g,
        (__attribute__((address_space(3))) u32*)l, 16, 0, 0);
}

#define OUT_CH 1548
#define NCHN   86
#define BPB    7925760   // per-batch output elements = 92160*86

// ---------------- prep kernels ----------------

__global__ void conv_w_kernel(const float* __restrict__ W0, unsigned short* __restrict__ Wb0,
                              const float* __restrict__ W1, unsigned short* __restrict__ Wb1) {
    int i = blockIdx.x * blockDim.x + threadIdx.x;
    if (i >= 297216) return;
    const float* W = W0;
    unsigned short* Wb = Wb0;
    if (i >= 99072) { W = W1; Wb = Wb1; i -= 99072; }
    const float4 f = ((const float4*)W)[i];
    short4v v;
    v[0] = (short)f2bf(f.x); v[1] = (short)f2bf(f.y);
    v[2] = (short)f2bf(f.z); v[3] = (short)f2bf(f.w);
    ((short4v*)Wb)[i] = v;
}

__global__ void transpose_x_kernel(const float* __restrict__ X, unsigned short* __restrict__ Xb,
                                   int C, int GG) {
    __shared__ float sT[64][65];
    const int p0 = blockIdx.x * 64;
    const int c0 = blockIdx.y * 64;
    const int b  = blockIdx.z;
    const int tid = threadIdx.x;
    const float* src = X + ((size_t)b * C + c0) * GG + p0;
    const int rc = tid >> 4;
    const int cp = (tid & 15) * 4;
    #pragma unroll
    for (int rr = 0; rr < 4; ++rr) {
        const int c = rc + rr * 16;
        const float4 f = *(const float4*)&src[(size_t)c * GG + cp];
        sT[c][cp + 0] = f.x; sT[c][cp + 1] = f.y;
        sT[c][cp + 2] = f.z; sT[c][cp + 3] = f.w;
    }
    __syncthreads();
    const int p  = tid >> 2;
    const int cg = (tid & 3) * 16;
    unsigned short u[16];
    #pragma unroll
    for (int k = 0; k < 16; ++k) u[k] = f2bf(sT[cg + k][p]);
    unsigned short* dst = Xb + ((size_t)b * GG + p0 + p) * C + c0 + cg;
    *(short8*)dst       = *(const short8*)&u[0];
    *(short8*)(dst + 8) = *(const short8*)&u[8];
}

// ---------------- main GEMM + decode (templated diagnostic) ----------------

template<int MODE, int REPS>
__global__ __launch_bounds__(512, 8) void detect_gemm(
    const unsigned short* __restrict__ Xb0, const unsigned short* __restrict__ Xb1,
    const unsigned short* __restrict__ Wb0, const unsigned short* __restrict__ Wb1,
    const float* __restrict__ b0, const float* __restrict__ b1,
    float* __restrict__ out, char* __restrict__ wsDiag)
{
    __shared__ __attribute__((aligned(128))) char smem[40960];
    unsigned short* sAbase = (unsigned short*)smem;
    unsigned short* sBbase = (unsigned short*)(smem + 16384);
    float* sOutF = (float*)smem;

    const int bid = blockIdx.x;
    const int v   = (bid & 7) * 1440 + (bid >> 3);
    const int mt  = v / 18;
    const int a   = v - mt * 18;

    const bool lvl1 = (mt >= 512);
    const unsigned short* __restrict__ Xb = lvl1 ? Xb1 : Xb0;
    const unsigned short* __restrict__ Wb = lvl1 ? Wb1 : Wb0;
    const float* __restrict__ biasA = (lvl1 ? b1 : b0) + a * NCHN;
    const int C   = lvl1 ? 512 : 256;
    const int GG  = lvl1 ? 1024 : 4096;
    const int Gsh = lvl1 ? 5 : 6;
    const float sxy     = lvl1 ? 1.1f : 1.2f;
    const float sxy_off = (sxy - 1.0f) * 0.5f;
    const float sf      = lvl1 ? 16.0f : 8.0f;
    const int shp  = a / 6;
    const int angi = a - shp * 6;
    const float aw = lvl1 ? ((shp == 0) ? 30.f : (shp == 1) ? 62.f : 59.f)
                          : ((shp == 0) ? 10.f : (shp == 1) ? 16.f : 33.f);
    const float ah = lvl1 ? ((shp == 0) ? 61.f : (shp == 1) ? 45.f : 119.f)
                          : ((shp == 0) ? 13.f : (shp == 1) ? 30.f : 23.f);
    const float aa = (angi == 0) ? -1.04719755119659775f :
                     (angi == 1) ? -0.52359877559829887f :
                     (angi == 2) ?  0.0f :
                     (angi == 3) ?  0.52359877559829887f :
                     (angi == 4) ?  1.04719755119659775f :
                                    1.57079632679489662f;

    const int tloc = lvl1 ? (mt - 512) : mt;
    const int b  = tloc >> (lvl1 ? 4 : 6);
    const int p0 = (tloc & ((lvl1 ? 16 : 64) - 1)) * 64;

    const unsigned short* __restrict__ Xp = Xb + ((size_t)b * GG + p0) * C;

    const int tid  = threadIdx.x;
    const int lane = tid & 63;
    const int wid  = tid >> 6;
    const int wm = wid >> 1;
    const int wn = wid & 1;

    f32x4 acc[3];
    #pragma unroll
    for (int j = 0; j < 3; ++j)
        acc[j] = f32x4{0.f, 0.f, 0.f, 0.f};

    const int rowIn = lane >> 3;
    const int scolE = ((((lane & 7) << 4)) ^ (rowIn << 4)) >> 1;

    const int lr   = lane & 15;
    const int kqb  = (lane >> 4) << 4;
    const int swzR = (lr & 7) << 4;

    const int KT = C >> 6;

    auto stage = [&](int bufsel, int kt) {
        const int k0 = kt << 6;
        unsigned short* sA = sAbase + bufsel * 4096;
        unsigned short* sB = sBbase + bufsel * 6144;
        {
            const int row = wid * 8 + rowIn;
            gload16(Xp + (size_t)row * C + k0 + scolE, (char*)sA + wid * 1024);
        }
        {
            const int n = wid * 8 + rowIn;
            int grow = a * NCHN + n;
            grow = grow > (OUT_CH - 1) ? (OUT_CH - 1) : grow;
            gload16(Wb + (size_t)grow * C + k0 + scolE, (char*)sB + wid * 1024);
        }
        if (wid < 4) {
            const int n = 64 + wid * 8 + rowIn;
            int grow = a * NCHN + n;
            grow = grow > (OUT_CH - 1) ? (OUT_CH - 1) : grow;
            gload16(Wb + (size_t)grow * C + k0 + scolE, (char*)sB + 8192 + wid * 1024);
        }
    };

    auto compute = [&](int bufsel) {
        const unsigned short* sA = sAbase + bufsel * 4096;
        const unsigned short* sB = sBbase + bufsel * 6144;
        #pragma unroll
        for (int kk = 0; kk < 2; ++kk) {
            const int cb = (kk << 6) + kqb;
            const int ra = wm * 16 + lr;
            const short8 af = *(const short8*)((const char*)sA + ra * 128 + (cb ^ swzR));
            short8 bfr[3];
            #pragma unroll
            for (int j = 0; j < 3; ++j) {
                const int rb = wn * 48 + j * 16 + lr;
                bfr[j] = *(const short8*)((const char*)sB + rb * 128 + (cb ^ swzR));
            }
            #pragma unroll
            for (int j = 0; j < 3; ++j)
                acc[j] = __builtin_amdgcn_mfma_f32_16x16x32_bf16(af, bfr[j], acc[j], 0, 0, 0);
        }
    };

    // ---- K-loop. MODE1 repeats the whole pipeline REPS times, acc carried
    // (not reinitialized) so no rep is dead code. ----
    const int kreps = (MODE == 1) ? REPS : 1;
    for (int rep = 0; rep < kreps; ++rep) {
        stage(0, 0);
        __syncthreads();
        int cur = 0;
        for (int kt = 0; kt < KT; ++kt) {
            if (kt + 1 < KT) stage(cur ^ 1, kt + 1);
            compute(cur);
            __syncthreads();
            cur ^= 1;
        }
    }

    if (MODE == 1) {
        // dump acc to ws window (keeps everything live); 1024-block window.
        f32x4* wsM1 = (f32x4*)wsDiag;
        const int base = ((bid & 1023) * 512 + tid) * 3;
        #pragma unroll
        for (int j = 0; j < 3; ++j)
            wsM1[base + j] = acc[j];
        return;
    }

    // ---- epilogue: decode -> LDS image -> contiguous nt float4 stores ----
    const int rq = (lane >> 4) * 4;
    const int lvloff = lvl1 ? 73728 : 0;
    const size_t spanDw = (size_t)b * BPB + ((size_t)(lvloff + a * GG + p0)) * NCHN;

    const int ereps = (MODE == 2) ? REPS : 1;
    float* outBase = out;
    size_t spanUse = spanDw;
    if (MODE == 2) {
        outBase = (float*)(wsDiag + (32u << 20));
        spanUse = spanDw & ((((size_t)1) << 23) - 1);   // 32MB dword window, alignment kept
    }

    for (int rep = 0; rep < ereps; ++rep) {
        if (MODE == 2) {
            // defeat LICM: force acc "modified" each rep so decode recomputes
            #pragma unroll
            for (int j = 0; j < 3; ++j) {
                float t0 = acc[j][0], t1 = acc[j][1], t2 = acc[j][2], t3 = acc[j][3];
                asm volatile("" : "+v"(t0), "+v"(t1), "+v"(t2), "+v"(t3));
                acc[j][0] = t0; acc[j][1] = t1; acc[j][2] = t2; acc[j][3] = t3;
            }
            __syncthreads();   // protect sOutF readers of previous rep
        }
        #pragma unroll
        for (int j = 0; j < 3; ++j) {
            const int ch = wn * 48 + j * 16 + lr;
            if (ch < NCHN) {
                const float bv = biasA[ch];
                #pragma unroll
                for (int r = 0; r < 4; ++r) {
                    const int px = wm * 16 + rq + r;
                    const int p  = p0 + px;
                    const float vv = acc[j][r] + bv;
                    float res;
                    if (ch == 0)      res = (sigm(vv) * sxy - sxy_off + (float)(p & ((1 << Gsh) - 1))) * sf;
                    else if (ch == 1) res = (sigm(vv) * sxy - sxy_off + (float)(p >> Gsh)) * sf;
                    else if (ch == 2) res = __expf(vv) * aw;
                    else if (ch == 3) res = __expf(vv) * ah;
                    else if (ch == 4) res = vv + aa;
                    else              res = sigm(vv);
                    sOutF[px * NCHN + ch] = res;
                }
            }
        }
        __syncthreads();
        #pragma unroll
        for (int k = 0; k < 3; ++k) {
            const int f4 = tid + k * 512;
            if (f4 < 1376) {
                const f32x4 vv = *(const f32x4*)&sOutF[f4 * 4];
                __builtin_nontemporal_store(vv, (f32x4*)&outBase[spanUse + f4 * 4]);
            }
        }
    }
}

extern "C" void kernel_launch(void* const* d_in, const int* in_sizes, int n_in,
                              void* d_out, int out_size, void* d_ws, size_t ws_size,
                              hipStream_t stream) {
    const float* x0 = (const float*)d_in[0];
    const float* x1 = (const float*)d_in[1];
    const float* W0 = (const float*)d_in[2];
    const float* b0 = (const float*)d_in[3];
    const float* W1 = (const float*)d_in[4];
    const float* b1 = (const float*)d_in[5];
    float* out = (float*)d_out;

    constexpr size_t XB0_OFF = 0;
    constexpr size_t XB1_OFF = 16777216;
    constexpr size_t WB0_OFF = 25165824;
    constexpr size_t WB1_OFF = 25958400;

    unsigned short* Xb0 = (unsigned short*)((char*)d_ws + XB0_OFF);
    unsigned short* Xb1 = (unsigned short*)((char*)d_ws + XB1_OFF);
    unsigned short* Wb0 = (unsigned short*)((char*)d_ws + WB0_OFF);
    unsigned short* Wb1 = (unsigned short*)((char*)d_ws + WB1_OFF);
    char* wsDiag = (char*)d_ws + (96u << 20);   // diagnostics scratch at +96MB

    hipLaunchKernelGGL(conv_w_kernel, dim3((297216 + 255) / 256), dim3(256), 0, stream,
                       W0, Wb0, W1, Wb1);
    hipLaunchKernelGGL(transpose_x_kernel, dim3(64, 4, 8), dim3(256), 0, stream,
                       x0, Xb0, 256, 4096);
    hipLaunchKernelGGL(transpose_x_kernel, dim3(16, 8, 8), dim3(256), 0, stream,
                       x1, Xb1, 512, 1024);

    const bool diag = (ws_size >= ((size_t)192 << 20));
    if (diag) {
        // D1: K-loop core x5
        hipLaunchKernelGGL((detect_gemm<1, 5>), dim3(11520), dim3(512), 0, stream,
                           Xb0, Xb1, Wb0, Wb1, b0, b1, out, wsDiag);
        // D2: K-loop once + epilogue x6 (to ws window)
        hipLaunchKernelGGL((detect_gemm<2, 6>), dim3(11520), dim3(512), 0, stream,
                           Xb0, Xb1, Wb0, Wb1, b0, b1, out, wsDiag);
    }
    // D3: real kernel (validated output)
    hipLaunchKernelGGL((detect_gemm<0, 1>), dim3(11520), dim3(512), 0, stream,
                       Xb0, Xb1, Wb0, Wb1, b0, b1, out, wsDiag);
}

// Round 10
// 186.835 us; speedup vs baseline: 4.8236x; 4.8236x over previous
//
#include <hip/hip_runtime.h>
#include <hip/hip_bf16.h>

// Detect head: prep (fp32->bf16 convert + x transpose) then fused MFMA GEMM + decode.
// R10 = R8 core with T3/T4 pipeline: triple-buffered LDS (3x24KB), counted
//     s_waitcnt vmcnt(3) + raw s_barrier per K-step (prefetch 2 tiles ahead,
//     never drain to 0 mid-loop). Uniform 3 global_load_lds per thread per
//     stage (B padded to 128 rows). Epilogue: LDS image + nt float4 stores.
//     BM=64 x BN=96(eff)/128(staged), BK=64, 11520 blocks, 512 thr, XCD swizzle.

typedef __attribute__((ext_vector_type(8))) short short8;
typedef __attribute__((ext_vector_type(4))) short short4v;
typedef __attribute__((ext_vector_type(4))) float f32x4;
typedef unsigned int u32;

__device__ __forceinline__ unsigned short f2bf(float f) {
    union { float f; unsigned u; } c; c.f = f;
    return (unsigned short)((c.u + 0x7fffu + ((c.u >> 16) & 1u)) >> 16);  // RTNE
}
__device__ __forceinline__ float sigm(float v) {
    return 1.0f / (1.0f + __expf(-v));
}
__device__ __forceinline__ void gload16(const void* g, void* l) {
    __builtin_amdgcn_global_load_lds(
        (const __attribute__((address_space(1))) u32*)g,
        (__attribute__((address_space(3))) u32*)l, 16, 0, 0);
}

#define OUT_CH 1548
#define NCHN   86
#define BPB    7925760   // per-batch output elements = 92160*86

// ---------------- prep kernels ----------------

__global__ void conv_w_kernel(const float* __restrict__ W0, unsigned short* __restrict__ Wb0,
                              const float* __restrict__ W1, unsigned short* __restrict__ Wb1) {
    int i = blockIdx.x * blockDim.x + threadIdx.x;
    if (i >= 297216) return;
    const float* W = W0;
    unsigned short* Wb = Wb0;
    if (i >= 99072) { W = W1; Wb = Wb1; i -= 99072; }
    const float4 f = ((const float4*)W)[i];
    short4v v;
    v[0] = (short)f2bf(f.x); v[1] = (short)f2bf(f.y);
    v[2] = (short)f2bf(f.z); v[3] = (short)f2bf(f.w);
    ((short4v*)Wb)[i] = v;
}

// x [B][C][GG] fp32 -> Xb [B][GG][C] bf16 (64x64 LDS tile transpose)
__global__ void transpose_x_kernel(const float* __restrict__ X, unsigned short* __restrict__ Xb,
                                   int C, int GG) {
    __shared__ float sT[64][65];
    const int p0 = blockIdx.x * 64;
    const int c0 = blockIdx.y * 64;
    const int b  = blockIdx.z;
    const int tid = threadIdx.x;
    const float* src = X + ((size_t)b * C + c0) * GG + p0;
    const int rc = tid >> 4;
    const int cp = (tid & 15) * 4;
    #pragma unroll
    for (int rr = 0; rr < 4; ++rr) {
        const int c = rc + rr * 16;
        const float4 f = *(const float4*)&src[(size_t)c * GG + cp];
        sT[c][cp + 0] = f.x; sT[c][cp + 1] = f.y;
        sT[c][cp + 2] = f.z; sT[c][cp + 3] = f.w;
    }
    __syncthreads();
    const int p  = tid >> 2;
    const int cg = (tid & 3) * 16;
    unsigned short u[16];
    #pragma unroll
    for (int k = 0; k < 16; ++k) u[k] = f2bf(sT[cg + k][p]);
    unsigned short* dst = Xb + ((size_t)b * GG + p0 + p) * C + c0 + cg;
    *(short8*)dst       = *(const short8*)&u[0];
    *(short8*)(dst + 8) = *(const short8*)&u[8];
}

// ---------------- main GEMM + decode ----------------

__global__ __launch_bounds__(512, 4) void detect_gemm(
    const unsigned short* __restrict__ Xb0, const unsigned short* __restrict__ Xb1,
    const unsigned short* __restrict__ Wb0, const unsigned short* __restrict__ Wb1,
    const float* __restrict__ b0, const float* __restrict__ b1,
    float* __restrict__ out)
{
    // LDS 72KB: 3 stage-buffers x 24KB (A 8KB + B 16KB). 2 blocks/CU.
    // Epilogue reuses the first 22KB as a flat [64*86] fp32 image.
    __shared__ __attribute__((aligned(128))) char smem[73728];
    float* sOutF = (float*)smem;

    // XCD swizzle: 11520 = 8 * 1440. Consecutive v within an XCD share the
    // same mtile across 18 anchors -> A-tile fetched once, L2-hit 17x.
    const int bid = blockIdx.x;
    const int v   = (bid & 7) * 1440 + (bid >> 3);
    const int mt  = v / 18;           // mtile 0..639
    const int a   = v - mt * 18;      // anchor 0..17

    const bool lvl1 = (mt >= 512);
    const unsigned short* __restrict__ Xb = lvl1 ? Xb1 : Xb0;
    const unsigned short* __restrict__ Wb = lvl1 ? Wb1 : Wb0;
    const float* __restrict__ biasA = (lvl1 ? b1 : b0) + a * NCHN;
    const int C   = lvl1 ? 512 : 256;
    const int GG  = lvl1 ? 1024 : 4096;
    const int Gsh = lvl1 ? 5 : 6;
    const float sxy     = lvl1 ? 1.1f : 1.2f;
    const float sxy_off = (sxy - 1.0f) * 0.5f;
    const float sf      = lvl1 ? 16.0f : 8.0f;
    const int shp  = a / 6;
    const int angi = a - shp * 6;
    const float aw = lvl1 ? ((shp == 0) ? 30.f : (shp == 1) ? 62.f : 59.f)
                          : ((shp == 0) ? 10.f : (shp == 1) ? 16.f : 33.f);
    const float ah = lvl1 ? ((shp == 0) ? 61.f : (shp == 1) ? 45.f : 119.f)
                          : ((shp == 0) ? 13.f : (shp == 1) ? 30.f : 23.f);
    const float aa = (angi == 0) ? -1.04719755119659775f :
                     (angi == 1) ? -0.52359877559829887f :
                     (angi == 2) ?  0.0f :
                     (angi == 3) ?  0.52359877559829887f :
                     (angi == 4) ?  1.04719755119659775f :
                                    1.57079632679489662f;

    const int tloc = lvl1 ? (mt - 512) : mt;
    const int b  = tloc >> (lvl1 ? 4 : 6);
    const int p0 = (tloc & ((lvl1 ? 16 : 64) - 1)) * 64;

    const unsigned short* __restrict__ Xp = Xb + ((size_t)b * GG + p0) * C;

    const int tid  = threadIdx.x;
    const int lane = tid & 63;
    const int wid  = tid >> 6;        // 0..7
    const int wm = wid >> 1;          // 0..3 : 16-pixel slice
    const int wn = wid & 1;           // 0..1 : 48-channel half

    f32x4 acc[3];
    #pragma unroll
    for (int j = 0; j < 3; ++j)
        acc[j] = f32x4{0.f, 0.f, 0.f, 0.f};

    // staging geometry: each wave-issue covers 8 rows (1KB, 128B row pitch);
    // lane covers base + lane*16 (HW rule). Source col pre-swizzled so the
    // linear LDS image is XOR-swizzled.
    const int rowIn = lane >> 3;                                  // 0..7
    const int scolE = ((((lane & 7) << 4)) ^ (rowIn << 4)) >> 1;  // element col in source

    const int lr   = lane & 15;
    const int kqb  = (lane >> 4) << 4;        // k-quarter byte offset in 64B half-row
    const int swzR = (lr & 7) << 4;           // read-side XOR

    const int KT = C >> 6;

    // B rows for this thread's two chunks (loop-invariant, clamped)
    const int nB1 = a * NCHN + wid * 8 + rowIn;
    const int nB2 = nB1 + 64;
    const int gB1 = nB1 > (OUT_CH - 1) ? (OUT_CH - 1) : nB1;
    const int gB2 = nB2 > (OUT_CH - 1) ? (OUT_CH - 1) : nB2;
    const int rowA = wid * 8 + rowIn;

    // stage: EXACTLY 3 global_load_lds per thread (uniform -> counted vmcnt).
    auto stage = [&](int bufsel, int kt) {
        const int k0 = kt << 6;
        char* base = smem + bufsel * 24576;
        gload16(Xp + (size_t)rowA * C + k0 + scolE, base + wid * 1024);           // A 8KB
        gload16(Wb + (size_t)gB1 * C + k0 + scolE, base + 8192 + wid * 1024);     // B rows 0-63
        gload16(Wb + (size_t)gB2 * C + k0 + scolE, base + 16384 + wid * 1024);    // B rows 64-127
    };

    auto compute = [&](int bufsel) {
        const char* base = smem + bufsel * 24576;
        #pragma unroll
        for (int kk = 0; kk < 2; ++kk) {
            const int cb = (kk << 6) + kqb;
            const int ra = wm * 16 + lr;
            const short8 af = *(const short8*)(base + ra * 128 + (cb ^ swzR));
            short8 bfr[3];
            #pragma unroll
            for (int j = 0; j < 3; ++j) {
                const int rb = wn * 48 + j * 16 + lr;
                bfr[j] = *(const short8*)(base + 8192 + rb * 128 + (cb ^ swzR));
            }
            #pragma unroll
            for (int j = 0; j < 3; ++j)
                acc[j] = __builtin_amdgcn_mfma_f32_16x16x32_bf16(af, bfr[j], acc[j], 0, 0, 0);
        }
    };

    // ---- T3/T4 K-loop: 3-deep buffers, counted vmcnt, raw barriers ----
    // prologue: 2 stages in flight (6 loads/thread)
    stage(0, 0);
    if (KT > 1) stage(1, 1);
    for (int kt = 0; kt < KT; ++kt) {
        if (kt < KT - 1) {
            // wait oldest stage only (3 loads of stage kt); stage kt+1 stays in flight
            asm volatile("s_waitcnt vmcnt(3)" ::: "memory");
        } else {
            asm volatile("s_waitcnt vmcnt(0)" ::: "memory");
        }
        __builtin_amdgcn_s_barrier();
        // stage kt+2 into buf (kt+2)%3 — all waves are past compute(kt-1),
        // which was the last reader of that buffer.
        if (kt + 2 < KT) stage((kt + 2) % 3, kt + 2);
        compute(kt % 3);
    }
    __syncthreads();   // all compute done before LDS is reused as sOutF

    // ---- epilogue: decode into flat LDS image [64 px][86 ch], then stream out ----
    // C/D layout: col(N)=lane&15, row(M)=(lane>>4)*4+reg
    const int rq = (lane >> 4) * 4;
    const int lvloff = lvl1 ? 73728 : 0;

    #pragma unroll
    for (int j = 0; j < 3; ++j) {
        const int ch = wn * 48 + j * 16 + lr;
        if (ch < NCHN) {
            const float bv = biasA[ch];
            #pragma unroll
            for (int r = 0; r < 4; ++r) {
                const int px = wm * 16 + rq + r;            // 0..63
                const int p  = p0 + px;                     // pixel in level grid
                const float vv = acc[j][r] + bv;
                float res;
                if (ch == 0)      res = (sigm(vv) * sxy - sxy_off + (float)(p & ((1 << Gsh) - 1))) * sf;
                else if (ch == 1) res = (sigm(vv) * sxy - sxy_off + (float)(p >> Gsh)) * sf;
                else if (ch == 2) res = __expf(vv) * aw;
                else if (ch == 3) res = __expf(vv) * ah;
                else if (ch == 4) res = vv + aa;
                else              res = sigm(vv);
                sOutF[px * NCHN + ch] = res;
            }
        }
    }
    __syncthreads();

    // stream out: block span = 64*86 = 5504 dwords, contiguous & 16B-aligned.
    // Non-temporal: write-once data, bypass L2 allocation.
    const size_t spanDw = (size_t)b * BPB + ((size_t)(lvloff + a * GG + p0)) * NCHN;
    #pragma unroll
    for (int k = 0; k < 3; ++k) {
        const int f4 = tid + k * 512;       // float4 index, 1376 total
        if (f4 < 1376) {
            const f32x4 vv = *(const f32x4*)&sOutF[f4 * 4];
            __builtin_nontemporal_store(vv, (f32x4*)&out[spanDw + f4 * 4]);
        }
    }
}

extern "C" void kernel_launch(void* const* d_in, const int* in_sizes, int n_in,
                              void* d_out, int out_size, void* d_ws, size_t ws_size,
                              hipStream_t stream) {
    const float* x0 = (const float*)d_in[0];
    const float* x1 = (const float*)d_in[1];
    const float* W0 = (const float*)d_in[2];
    const float* b0 = (const float*)d_in[3];
    const float* W1 = (const float*)d_in[4];
    const float* b1 = (const float*)d_in[5];
    float* out = (float*)d_out;

    constexpr size_t XB0_OFF = 0;            // 8*4096*256*2  = 16777216
    constexpr size_t XB1_OFF = 16777216;     // 8*1024*512*2  =  8388608
    constexpr size_t WB0_OFF = 25165824;     // 1548*256*2    =   792576
    constexpr size_t WB1_OFF = 25958400;     // 1548*512*2    =  1585152

    unsigned short* Xb0 = (unsigned short*)((char*)d_ws + XB0_OFF);
    unsigned short* Xb1 = (unsigned short*)((char*)d_ws + XB1_OFF);
    unsigned short* Wb0 = (unsigned short*)((char*)d_ws + WB0_OFF);
    unsigned short* Wb1 = (unsigned short*)((char*)d_ws + WB1_OFF);

    hipLaunchKernelGGL(conv_w_kernel, dim3((297216 + 255) / 256), dim3(256), 0, stream,
                       W0, Wb0, W1, Wb1);
    hipLaunchKernelGGL(transpose_x_kernel, dim3(64, 4, 8), dim3(256), 0, stream,
                       x0, Xb0, 256, 4096);
    hipLaunchKernelGGL(transpose_x_kernel, dim3(16, 8, 8), dim3(256), 0, stream,
                       x1, Xb1, 512, 1024);

    // 640 mtiles (512 lvl0 + 128 lvl1) x 18 anchors = 11520 blocks
    hipLaunchKernelGGL(detect_gemm, dim3(11520), dim3(512), 0, stream,
                       Xb0, Xb1, Wb0, Wb1, b0, b1, out);
}